// Round 15
// baseline (346.330 us; speedup 1.0000x reference)
//
#include <hip/hip_runtime.h>

typedef unsigned short u16;
typedef __attribute__((ext_vector_type(8))) unsigned short u16x8;
typedef __attribute__((ext_vector_type(8))) __bf16 bf16x8;
typedef __attribute__((ext_vector_type(4))) float f32x4;

#define M_ROWS 65536   // b*s*f
#define KDIM   512
#define NKT    8       // KDIM / 64

typedef __attribute__((address_space(1))) const void gconst_void;
typedef __attribute__((address_space(3))) void lds_void;

static __device__ __forceinline__ u16 f2bf(float f) {
  unsigned u = __builtin_bit_cast(unsigned, f);
  u += 0x7FFFu + ((u >> 16) & 1u);
  return (u16)(u >> 16);
}

static __device__ __forceinline__ f32x4 mfma_bf16(u16x8 a, u16x8 b, f32x4 c) {
  return __builtin_amdgcn_mfma_f32_16x16x32_bf16(
      __builtin_bit_cast(bf16x8, a), __builtin_bit_cast(bf16x8, b), c, 0, 0, 0);
}

// ---------------- fp32 -> bf16 convert (x) ----------------
__global__ void conv_x(const float* __restrict__ x, u16* __restrict__ xb) {
  const size_t t = (size_t)blockIdx.x * 256 + threadIdx.x;
  f32x4 a = *(const f32x4*)(x + t * 8);
  f32x4 b = *(const f32x4*)(x + t * 8 + 4);
  u16x8 w;
#pragma unroll
  for (int e = 0; e < 4; ++e) { w[e] = f2bf(a[e]); w[e + 4] = f2bf(b[e]); }
  *(u16x8*)(xb + t * 8) = w;
}

// ------ weight transpose+convert, LDS-tiled ------
__global__ void convW_qkv_t(const float* __restrict__ Wq, const float* __restrict__ Wk,
                            const float* __restrict__ Wv, u16* __restrict__ Wt) {
  __shared__ float tile[32][33];
  const int bn = blockIdx.x * 32;
  const int bk = blockIdx.y * 32;
  const int tx = threadIdx.x & 31, ty = threadIdx.x >> 5;
  const float* W = (bn < 512) ? Wq : ((bn < 1024) ? Wk : Wv);
  const int coln = bn & 511;
#pragma unroll
  for (int r = 0; r < 32; r += 8)
    tile[ty + r][tx] = W[(size_t)(bk + ty + r) * 512 + coln + tx];
  __syncthreads();
#pragma unroll
  for (int r = 0; r < 32; r += 8)
    Wt[(size_t)(bn + ty + r) * 512 + bk + tx] = f2bf(tile[tx][ty + r]);
}

__global__ void convWo_t(const float* __restrict__ Wo, u16* __restrict__ Wt) {
  __shared__ float tile[32][33];
  const int bn = blockIdx.x * 32;
  const int bk = blockIdx.y * 32;
  const int tx = threadIdx.x & 31, ty = threadIdx.x >> 5;
#pragma unroll
  for (int r = 0; r < 32; r += 8)
    tile[ty + r][tx] = Wo[(size_t)(bk + ty + r) * 512 + bn + tx];
  __syncthreads();
#pragma unroll
  for (int r = 0; r < 32; r += 8)
    Wt[(size_t)(bn + ty + r) * 512 + bk + tx] = f2bf(tile[tx][ty + r]);
}

// -------- FUSED qkv projection (one head) + attention, B in registers -----
// r13 structure with the B operand moved OUT of LDS: B fragments (head-h
// weight rows, L2-resident, re-read by every block) are loaded directly
// from global as u16x8 (16B/lane, 64B/row cache-line groups).  Cuts LDS
// traffic per K-tile from 152 KB to 80 KB (-47%) -- LDS aggregate BW was
// the binding resource (r14 cycle accounting).  A stays LDS-staged with
// the proven swizzle; sync = r13's simple tile-top vmcnt(0)+barrier.
// LDS 54 KiB (A dbuf 32K during loop; qkvT+Pl alias after).
__global__ __launch_bounds__(512, 4)
void gemm_qkv_attn(const u16* __restrict__ A, const u16* __restrict__ Wt,
                   const float* __restrict__ pos_bias, u16* __restrict__ attnbuf) {
  __shared__ __attribute__((aligned(16))) u16 smem[27648];  // 54 KiB
  u16* Ab   = smem;            // [2][8192] (32 KiB, K-loop)
  u16* qkvT = smem;            // [128][200] = 25600 (post-loop alias)
  u16* Pl   = smem + 25600;    // [8][256]  = 2048

  const int tid  = threadIdx.x;
  const int lane = tid & 63;
  const int wid  = tid >> 6;        // 0..7
  const int wm   = wid >> 2;        // 0..1 (64-row band)
  const int wn   = wid & 3;         // 0..3 (48-col band)
  const int lg   = lane >> 4;
  const int lc   = lane & 15;
  const int srow = lane >> 3;       // 0..7
  const int sg   = (lane & 7) ^ srow;

  const int nwg  = gridDim.x;       // 4096
  const int cpx  = nwg >> 3;
  const int flat = blockIdx.x;
  const int swz  = (flat & 7) * cpx + (flat >> 3);
  const int mt   = swz >> 3;
  const int h    = swz & 7;
  const int row0 = mt * 128;

  auto stageA = [&](int buf, int unit, int kt) {
    const int rl = unit * 64 + wid * 8;
    const u16* src = A + (size_t)(row0 + rl + srow) * KDIM + kt * 64 + sg * 8;
    __builtin_amdgcn_global_load_lds((gconst_void*)src,
                                     (lds_void*)&Ab[buf * 8192 + rl * 64], 16, 0, 0);
  };

  // B fragment row pointers (per ni): n = wn*48+ni*16+lc -> q|k|v section
  const u16* Bw[3];
#pragma unroll
  for (int ni = 0; ni < 3; ++ni) {
    const int n    = wn * 48 + ni * 16 + lc;
    const int grow = (n >> 6) * 512 + h * 64 + (n & 63);
    Bw[ni] = Wt + (size_t)grow * KDIM;
  }

  f32x4 acc[4][3];
#pragma unroll
  for (int mi = 0; mi < 4; ++mi)
#pragma unroll
    for (int ni = 0; ni < 3; ++ni) acc[mi][ni] = (f32x4){0.f, 0.f, 0.f, 0.f};

  stageA(0, 0, 0); stageA(0, 1, 0);
  asm volatile("s_waitcnt vmcnt(0)" ::: "memory");
  __builtin_amdgcn_s_barrier();

  for (int t = 0; t < NKT; ++t) {
    const int  c   = t & 1;
    const bool pre = (t + 1) < NKT;

    if (pre) { stageA(c ^ 1, 0, t + 1); stageA(c ^ 1, 1, t + 1); }

#pragma unroll
    for (int ks = 0; ks < 2; ++ks) {
      const int gsw = ((ks * 4 + lg) ^ (lc & 7)) << 3;
      u16x8 bfr[3], af[4];
#pragma unroll
      for (int ni = 0; ni < 3; ++ni)
        bfr[ni] = *(const u16x8*)(Bw[ni] + t * 64 + ks * 32 + lg * 8);
#pragma unroll
      for (int i = 0; i < 4; ++i)
        af[i] = *(const u16x8*)&Ab[c * 8192 + (wm * 64 + i * 16 + lc) * 64 + gsw];
#pragma unroll
      for (int i = 0; i < 4; ++i)
#pragma unroll
        for (int ni = 0; ni < 3; ++ni)
          acc[i][ni] = mfma_bf16(af[i], bfr[ni], acc[i][ni]);
    }

    asm volatile("s_waitcnt vmcnt(0)" ::: "memory");
    __builtin_amdgcn_s_barrier();
  }

  // ---- epilogue: acc -> bf16 -> qkvT[128][200] (aliases Ab) ----
#pragma unroll
  for (int mi = 0; mi < 4; ++mi)
#pragma unroll
    for (int ni = 0; ni < 3; ++ni) {
      const int col = wn * 48 + ni * 16 + lc;
      const int rb  = wm * 64 + mi * 16 + lg * 4;
#pragma unroll
      for (int r = 0; r < 4; ++r)
        qkvT[(rb + r) * 200 + col] = f2bf(acc[mi][ni][r]);
    }
  __syncthreads();

  // ---- attention (verified math): one token per wave ----
  const float scale = 0.125f;
  const f32x4 zf = {0.f, 0.f, 0.f, 0.f};
  const int rb = wid * 16;
  const int qb = (rb + lc) * 200;

  u16x8 aq0 = *(const u16x8*)&qkvT[qb + 0  + lg * 8];
  u16x8 aq1 = *(const u16x8*)&qkvT[qb + 32 + lg * 8];
  u16x8 bk0 = *(const u16x8*)&qkvT[qb + 64 + lg * 8];
  u16x8 bk1 = *(const u16x8*)&qkvT[qb + 96 + lg * 8];
  f32x4 s = mfma_bf16(aq0, bk0, zf);
  s = mfma_bf16(aq1, bk1, s);

  const int pb = wid * 256;
#pragma unroll
  for (int r = 0; r < 4; ++r) {
    const int i = lg * 4 + r;
    float sv = s[r] * scale + pos_bias[h * 256 + i * 16 + lc];
    if (lc > i) sv = -1e30f;
    float m = sv;
#pragma unroll
    for (int off = 8; off >= 1; off >>= 1) m = fmaxf(m, __shfl_xor(m, off));
    float e = __expf(sv - m);
    float sm = e;
#pragma unroll
    for (int off = 8; off >= 1; off >>= 1) sm += __shfl_xor(sm, off);
    Pl[pb + i * 16 + lc] = f2bf(e / sm);
  }
  asm volatile("s_waitcnt lgkmcnt(0)" ::: "memory");

  u16x8 ap = {0, 0, 0, 0, 0, 0, 0, 0};
  if (lane < 32) ap = *(const u16x8*)&Pl[pb + lc * 16 + lg * 8];

#pragma unroll
  for (int nd = 0; nd < 4; ++nd) {
    u16x8 bv = {0, 0, 0, 0, 0, 0, 0, 0};
    if (lane < 32) {
#pragma unroll
      for (int jj = 0; jj < 8; ++jj) {
        const int j = lg * 8 + jj;
        bv[jj] = qkvT[(rb + j) * 200 + 128 + nd * 16 + lc];
      }
    }
    f32x4 o = mfma_bf16(ap, bv, zf);
#pragma unroll
    for (int r = 0; r < 4; ++r) {
      const int i = lg * 4 + r;
      attnbuf[(size_t)(row0 + rb + i) * 512 + h * 64 + nd * 16 + lc] = f2bf(o[r]);
    }
  }
}

// -------- GEMM2: out = attnbuf @ Wo_t^T + bo, 128x128, B in registers ----
// Same surgery: B (Wo_t, 512 KiB, L2-resident) loaded directly to regs;
// LDS = A dbuf only (32 KiB); __launch_bounds__(512,6) -> 3 blocks/CU.
__global__ __launch_bounds__(512, 6)
void gemm_out(const u16* __restrict__ A, const u16* __restrict__ Bt,
              float* __restrict__ C, const float* __restrict__ bias) {
  __shared__ __attribute__((aligned(16))) u16 smem[16384];  // 32 KiB
  u16* Ab = smem;            // [2][8192]

  const int tid  = threadIdx.x;
  const int lane = tid & 63;
  const int wid  = tid >> 6;
  const int wm   = wid >> 2;        // 0..1 (64-row band)
  const int wn   = wid & 3;         // 0..3 (32-col band)
  const int lg   = lane >> 4;
  const int lc   = lane & 15;
  const int srow = lane >> 3;
  const int sg   = (lane & 7) ^ srow;

  const int nwg  = gridDim.x;       // 2048
  const int cpx  = nwg >> 3;
  const int flat = blockIdx.x;
  const int swz  = (flat & 7) * cpx + (flat >> 3);
  const int mt   = swz >> 2;        // 0..511
  const int nt   = swz & 3;         // 0..3
  const int row0 = mt * 128, col0 = nt * 128;

  auto stageA = [&](int buf, int unit, int kt) {
    const int rl = unit * 64 + wid * 8;
    const u16* src = A + (size_t)(row0 + rl + srow) * KDIM + kt * 64 + sg * 8;
    __builtin_amdgcn_global_load_lds((gconst_void*)src,
                                     (lds_void*)&Ab[buf * 8192 + rl * 64], 16, 0, 0);
  };

  const u16* Bw[2];
#pragma unroll
  for (int ni = 0; ni < 2; ++ni)
    Bw[ni] = Bt + (size_t)(col0 + wn * 32 + ni * 16 + lc) * KDIM;

  f32x4 acc[4][2];
#pragma unroll
  for (int mi = 0; mi < 4; ++mi)
#pragma unroll
    for (int ni = 0; ni < 2; ++ni) acc[mi][ni] = (f32x4){0.f, 0.f, 0.f, 0.f};

  stageA(0, 0, 0); stageA(0, 1, 0);
  asm volatile("s_waitcnt vmcnt(0)" ::: "memory");
  __builtin_amdgcn_s_barrier();

  for (int t = 0; t < NKT; ++t) {
    const int  c   = t & 1;
    const bool pre = (t + 1) < NKT;

    if (pre) { stageA(c ^ 1, 0, t + 1); stageA(c ^ 1, 1, t + 1); }

#pragma unroll
    for (int ks = 0; ks < 2; ++ks) {
      const int gsw = ((ks * 4 + lg) ^ (lc & 7)) << 3;
      u16x8 bfr[2], af[4];
#pragma unroll
      for (int ni = 0; ni < 2; ++ni)
        bfr[ni] = *(const u16x8*)(Bw[ni] + t * 64 + ks * 32 + lg * 8);
#pragma unroll
      for (int i = 0; i < 4; ++i)
        af[i] = *(const u16x8*)&Ab[c * 8192 + (wm * 64 + i * 16 + lc) * 64 + gsw];
#pragma unroll
      for (int i = 0; i < 4; ++i)
#pragma unroll
        for (int ni = 0; ni < 2; ++ni)
          acc[i][ni] = mfma_bf16(af[i], bfr[ni], acc[i][ni]);
    }

    asm volatile("s_waitcnt vmcnt(0)" ::: "memory");
    __builtin_amdgcn_s_barrier();
  }

  // epilogue (global only)
  const int gmb = row0 + wm * 64;
  const int gnb = col0 + wn * 32;
#pragma unroll
  for (int mi = 0; mi < 4; ++mi)
#pragma unroll
    for (int ni = 0; ni < 2; ++ni) {
      const int gm = gmb + mi * 16 + lg * 4;
      const int gn = gnb + ni * 16 + lc;
      const float bv = bias[gn];
      f32x4 v = acc[mi][ni];
#pragma unroll
      for (int r = 0; r < 4; ++r) C[(size_t)(gm + r) * 512 + gn] = v[r] + bv;
    }
}

// ---------------- launch ----------------
extern "C" void kernel_launch(void* const* d_in, const int* in_sizes, int n_in,
                              void* d_out, int out_size, void* d_ws, size_t ws_size,
                              hipStream_t stream) {
  const float* x        = (const float*)d_in[0];
  const float* pos_bias = (const float*)d_in[1];
  const float* Wq       = (const float*)d_in[2];
  const float* Wk       = (const float*)d_in[3];
  const float* Wv       = (const float*)d_in[4];
  const float* Wo       = (const float*)d_in[5];
  const float* bo       = (const float*)d_in[6];
  float* out            = (float*)d_out;

  u16* xb      = (u16*)d_ws;                           // [65536][512]
  u16* attnbuf = xb + (size_t)M_ROWS * 512;            // [65536][512]
  u16* Wo_t    = attnbuf + (size_t)M_ROWS * 512;       // [512][512]
  u16* Wqkv_t  = (u16*)d_out;                          // [1536][512] (dead until GEMM2)

  conv_x<<<dim3(M_ROWS * KDIM / (256 * 8)), dim3(256), 0, stream>>>(x, xb);
  convW_qkv_t<<<dim3(48, 16), dim3(256), 0, stream>>>(Wq, Wk, Wv, Wqkv_t);
  gemm_qkv_attn<<<dim3(4096), dim3(512), 0, stream>>>(xb, Wqkv_t, pos_bias, attnbuf);
  convWo_t<<<dim3(16, 16), dim3(256), 0, stream>>>(Wo, Wo_t);
  gemm_out<<<dim3(2048), dim3(512), 0, stream>>>(attnbuf, Wo_t, out, bo);
}

// Round 16
// 327.934 us; speedup vs baseline: 1.0561x; 1.0561x over previous
//
#include <hip/hip_runtime.h>

typedef unsigned short u16;
typedef __attribute__((ext_vector_type(8))) unsigned short u16x8;
typedef __attribute__((ext_vector_type(8))) __bf16 bf16x8;
typedef __attribute__((ext_vector_type(4))) float f32x4;

#define M_ROWS 65536   // b*s*f
#define KDIM   512
#define NKT    8       // KDIM / 64

typedef __attribute__((address_space(1))) const void gconst_void;
typedef __attribute__((address_space(3))) void lds_void;

static __device__ __forceinline__ u16 f2bf(float f) {
  unsigned u = __builtin_bit_cast(unsigned, f);
  u += 0x7FFFu + ((u >> 16) & 1u);
  return (u16)(u >> 16);
}

static __device__ __forceinline__ f32x4 mfma_bf16(u16x8 a, u16x8 b, f32x4 c) {
  return __builtin_amdgcn_mfma_f32_16x16x32_bf16(
      __builtin_bit_cast(bf16x8, a), __builtin_bit_cast(bf16x8, b), c, 0, 0, 0);
}

// ---------------- fp32 -> bf16 convert (x) ----------------
__global__ void conv_x(const float* __restrict__ x, u16* __restrict__ xb) {
  const size_t t = (size_t)blockIdx.x * 256 + threadIdx.x;
  f32x4 a = *(const f32x4*)(x + t * 8);
  f32x4 b = *(const f32x4*)(x + t * 8 + 4);
  u16x8 w;
#pragma unroll
  for (int e = 0; e < 4; ++e) { w[e] = f2bf(a[e]); w[e + 4] = f2bf(b[e]); }
  *(u16x8*)(xb + t * 8) = w;
}

// ------ weight transpose+convert, LDS-tiled ------
__global__ void convW_qkv_t(const float* __restrict__ Wq, const float* __restrict__ Wk,
                            const float* __restrict__ Wv, u16* __restrict__ Wt) {
  __shared__ float tile[32][33];
  const int bn = blockIdx.x * 32;
  const int bk = blockIdx.y * 32;
  const int tx = threadIdx.x & 31, ty = threadIdx.x >> 5;
  const float* W = (bn < 512) ? Wq : ((bn < 1024) ? Wk : Wv);
  const int coln = bn & 511;
#pragma unroll
  for (int r = 0; r < 32; r += 8)
    tile[ty + r][tx] = W[(size_t)(bk + ty + r) * 512 + coln + tx];
  __syncthreads();
#pragma unroll
  for (int r = 0; r < 32; r += 8)
    Wt[(size_t)(bn + ty + r) * 512 + bk + tx] = f2bf(tile[tx][ty + r]);
}

__global__ void convWo_t(const float* __restrict__ Wo, u16* __restrict__ Wt) {
  __shared__ float tile[32][33];
  const int bn = blockIdx.x * 32;
  const int bk = blockIdx.y * 32;
  const int tx = threadIdx.x & 31, ty = threadIdx.x >> 5;
#pragma unroll
  for (int r = 0; r < 32; r += 8)
    tile[ty + r][tx] = Wo[(size_t)(bk + ty + r) * 512 + bn + tx];
  __syncthreads();
#pragma unroll
  for (int r = 0; r < 32; r += 8)
    Wt[(size_t)(bn + ty + r) * 512 + bk + tx] = f2bf(tile[tx][ty + r]);
}

// -------- FUSED qkv projection + attention, B in regs w/ T14 prefetch -----
// r15's B-in-registers (LDS traffic -47%) FIXED per T14: B(t+1)'s 6 gathers
// are issued at the TOP of tile t (alongside the A stage) into bB[], and
// consumed a full tile later from bA[] -- the compute window (>>L2 latency)
// hides the gather.  bA<-bB copy uses compile-time indices only (rule #20).
// A stays LDS-staged+swizzled; sync = r13's tile-top vmcnt(0)+barrier.
__global__ __launch_bounds__(512, 4)
void gemm_qkv_attn(const u16* __restrict__ A, const u16* __restrict__ Wt,
                   const float* __restrict__ pos_bias, u16* __restrict__ attnbuf) {
  __shared__ __attribute__((aligned(16))) u16 smem[27648];  // 54 KiB
  u16* Ab   = smem;            // [2][8192] (32 KiB, K-loop)
  u16* qkvT = smem;            // [128][200] = 25600 (post-loop alias)
  u16* Pl   = smem + 25600;    // [8][256]  = 2048

  const int tid  = threadIdx.x;
  const int lane = tid & 63;
  const int wid  = tid >> 6;        // 0..7
  const int wm   = wid >> 2;        // 0..1 (64-row band)
  const int wn   = wid & 3;         // 0..3 (48-col band)
  const int lg   = lane >> 4;
  const int lc   = lane & 15;
  const int srow = lane >> 3;       // 0..7
  const int sg   = (lane & 7) ^ srow;

  const int nwg  = gridDim.x;       // 4096
  const int cpx  = nwg >> 3;
  const int flat = blockIdx.x;
  const int swz  = (flat & 7) * cpx + (flat >> 3);
  const int mt   = swz >> 3;
  const int h    = swz & 7;
  const int row0 = mt * 128;

  auto stageA = [&](int buf, int unit, int kt) {
    const int rl = unit * 64 + wid * 8;
    const u16* src = A + (size_t)(row0 + rl + srow) * KDIM + kt * 64 + sg * 8;
    __builtin_amdgcn_global_load_lds((gconst_void*)src,
                                     (lds_void*)&Ab[buf * 8192 + rl * 64], 16, 0, 0);
  };

  // B fragment row pointers (per ni): n = wn*48+ni*16+lc -> q|k|v section
  const u16* Bw[3];
#pragma unroll
  for (int ni = 0; ni < 3; ++ni) {
    const int n    = wn * 48 + ni * 16 + lc;
    const int grow = (n >> 6) * 512 + h * 64 + (n & 63);
    Bw[ni] = Wt + (size_t)grow * KDIM;
  }

  f32x4 acc[4][3];
#pragma unroll
  for (int mi = 0; mi < 4; ++mi)
#pragma unroll
    for (int ni = 0; ni < 3; ++ni) acc[mi][ni] = (f32x4){0.f, 0.f, 0.f, 0.f};

  u16x8 bA[6], bB[6];   // [ni*2+ks], double-buffered across tiles

  // prologue: A(0)->LDS, B(0)->bA
  stageA(0, 0, 0); stageA(0, 1, 0);
#pragma unroll
  for (int ni = 0; ni < 3; ++ni)
#pragma unroll
    for (int ks = 0; ks < 2; ++ks)
      bA[ni * 2 + ks] = *(const u16x8*)(Bw[ni] + 0 * 64 + ks * 32 + lg * 8);
  asm volatile("s_waitcnt vmcnt(0)" ::: "memory");
  __builtin_amdgcn_s_barrier();

  for (int t = 0; t < NKT; ++t) {
    const int  c   = t & 1;
    const bool pre = (t + 1) < NKT;

    // issue-early: next tile's A stage + B gathers (consumed next iteration)
    if (pre) {
      stageA(c ^ 1, 0, t + 1); stageA(c ^ 1, 1, t + 1);
#pragma unroll
      for (int ni = 0; ni < 3; ++ni)
#pragma unroll
        for (int ks = 0; ks < 2; ++ks)
          bB[ni * 2 + ks] = *(const u16x8*)(Bw[ni] + (t + 1) * 64 + ks * 32 + lg * 8);
    }

#pragma unroll
    for (int ks = 0; ks < 2; ++ks) {
      const int gsw = ((ks * 4 + lg) ^ (lc & 7)) << 3;
      u16x8 af[4];
#pragma unroll
      for (int i = 0; i < 4; ++i)
        af[i] = *(const u16x8*)&Ab[c * 8192 + (wm * 64 + i * 16 + lc) * 64 + gsw];
#pragma unroll
      for (int i = 0; i < 4; ++i)
#pragma unroll
        for (int ni = 0; ni < 3; ++ni)
          acc[i][ni] = mfma_bf16(af[i], bA[ni * 2 + ks], acc[i][ni]);
    }

    if (pre) {
#pragma unroll
      for (int u = 0; u < 6; ++u) bA[u] = bB[u];   // consume-late swap
    }
    asm volatile("s_waitcnt vmcnt(0)" ::: "memory");
    __builtin_amdgcn_s_barrier();
  }

  // ---- epilogue: acc -> bf16 -> qkvT[128][200] (aliases Ab) ----
#pragma unroll
  for (int mi = 0; mi < 4; ++mi)
#pragma unroll
    for (int ni = 0; ni < 3; ++ni) {
      const int col = wn * 48 + ni * 16 + lc;
      const int rb  = wm * 64 + mi * 16 + lg * 4;
#pragma unroll
      for (int r = 0; r < 4; ++r)
        qkvT[(rb + r) * 200 + col] = f2bf(acc[mi][ni][r]);
    }
  __syncthreads();

  // ---- attention (verified math): one token per wave ----
  const float scale = 0.125f;
  const f32x4 zf = {0.f, 0.f, 0.f, 0.f};
  const int rb = wid * 16;
  const int qb = (rb + lc) * 200;

  u16x8 aq0 = *(const u16x8*)&qkvT[qb + 0  + lg * 8];
  u16x8 aq1 = *(const u16x8*)&qkvT[qb + 32 + lg * 8];
  u16x8 bk0 = *(const u16x8*)&qkvT[qb + 64 + lg * 8];
  u16x8 bk1 = *(const u16x8*)&qkvT[qb + 96 + lg * 8];
  f32x4 s = mfma_bf16(aq0, bk0, zf);
  s = mfma_bf16(aq1, bk1, s);

  const int pb = wid * 256;
#pragma unroll
  for (int r = 0; r < 4; ++r) {
    const int i = lg * 4 + r;
    float sv = s[r] * scale + pos_bias[h * 256 + i * 16 + lc];
    if (lc > i) sv = -1e30f;
    float m = sv;
#pragma unroll
    for (int off = 8; off >= 1; off >>= 1) m = fmaxf(m, __shfl_xor(m, off));
    float e = __expf(sv - m);
    float sm = e;
#pragma unroll
    for (int off = 8; off >= 1; off >>= 1) sm += __shfl_xor(sm, off);
    Pl[pb + i * 16 + lc] = f2bf(e / sm);
  }
  asm volatile("s_waitcnt lgkmcnt(0)" ::: "memory");

  u16x8 ap = {0, 0, 0, 0, 0, 0, 0, 0};
  if (lane < 32) ap = *(const u16x8*)&Pl[pb + lc * 16 + lg * 8];

#pragma unroll
  for (int nd = 0; nd < 4; ++nd) {
    u16x8 bv = {0, 0, 0, 0, 0, 0, 0, 0};
    if (lane < 32) {
#pragma unroll
      for (int jj = 0; jj < 8; ++jj) {
        const int j = lg * 8 + jj;
        bv[jj] = qkvT[(rb + j) * 200 + 128 + nd * 16 + lc];
      }
    }
    f32x4 o = mfma_bf16(ap, bv, zf);
#pragma unroll
    for (int r = 0; r < 4; ++r) {
      const int i = lg * 4 + r;
      attnbuf[(size_t)(row0 + rb + i) * 512 + h * 64 + nd * 16 + lc] = f2bf(o[r]);
    }
  }
}

// -------- GEMM2: out = attnbuf @ Wo_t^T + bo, 128x128, 2 blk/CU -----
// (r14 measured-good form: B in LDS, 64 KiB, simple tile-top sync.)
__global__ __launch_bounds__(512, 4)
void gemm_out(const u16* __restrict__ A, const u16* __restrict__ Bt,
              float* __restrict__ C, const float* __restrict__ bias) {
  __shared__ __attribute__((aligned(16))) u16 smem[32768];  // 64 KiB
  u16* Ab = smem;            // [2][8192]
  u16* Bb = smem + 16384;    // [2][8192]

  const int tid  = threadIdx.x;
  const int lane = tid & 63;
  const int wid  = tid >> 6;
  const int wm   = wid >> 2;        // 0..1 (64-row band)
  const int wn   = wid & 3;         // 0..3 (32-col band)
  const int lg   = lane >> 4;
  const int lc   = lane & 15;
  const int srow = lane >> 3;
  const int sg   = (lane & 7) ^ srow;

  const int nwg  = gridDim.x;       // 2048
  const int cpx  = nwg >> 3;
  const int flat = blockIdx.x;
  const int swz  = (flat & 7) * cpx + (flat >> 3);
  const int mt   = swz >> 2;        // 0..511
  const int nt   = swz & 3;         // 0..3
  const int row0 = mt * 128, col0 = nt * 128;

  auto stageA = [&](int buf, int unit, int kt) {
    const int rl = unit * 64 + wid * 8;
    const u16* src = A + (size_t)(row0 + rl + srow) * KDIM + kt * 64 + sg * 8;
    __builtin_amdgcn_global_load_lds((gconst_void*)src,
                                     (lds_void*)&Ab[buf * 8192 + rl * 64], 16, 0, 0);
  };
  auto stageB = [&](int buf, int unit, int kt) {
    const int rl = unit * 64 + wid * 8;
    const u16* src = Bt + (size_t)(col0 + rl + srow) * KDIM + kt * 64 + sg * 8;
    __builtin_amdgcn_global_load_lds((gconst_void*)src,
                                     (lds_void*)&Bb[buf * 8192 + rl * 64], 16, 0, 0);
  };

  f32x4 acc[4][2];
#pragma unroll
  for (int mi = 0; mi < 4; ++mi)
#pragma unroll
    for (int ni = 0; ni < 2; ++ni) acc[mi][ni] = (f32x4){0.f, 0.f, 0.f, 0.f};

  stageA(0, 0, 0); stageA(0, 1, 0);
  stageB(0, 0, 0); stageB(0, 1, 0);
  asm volatile("s_waitcnt vmcnt(0)" ::: "memory");
  __builtin_amdgcn_s_barrier();

  for (int t = 0; t < NKT; ++t) {
    const int  c   = t & 1;
    const bool pre = (t + 1) < NKT;

    if (pre) {
      stageA(c ^ 1, 0, t + 1); stageA(c ^ 1, 1, t + 1);
      stageB(c ^ 1, 0, t + 1); stageB(c ^ 1, 1, t + 1);
    }

#pragma unroll
    for (int ks = 0; ks < 2; ++ks) {
      const int gsw = ((ks * 4 + lg) ^ (lc & 7)) << 3;
      u16x8 bfr[2], af[4];
#pragma unroll
      for (int ni = 0; ni < 2; ++ni)
        bfr[ni] = *(const u16x8*)&Bb[c * 8192 + (wn * 32 + ni * 16 + lc) * 64 + gsw];
#pragma unroll
      for (int i = 0; i < 4; ++i)
        af[i] = *(const u16x8*)&Ab[c * 8192 + (wm * 64 + i * 16 + lc) * 64 + gsw];
#pragma unroll
      for (int i = 0; i < 4; ++i)
#pragma unroll
        for (int ni = 0; ni < 2; ++ni)
          acc[i][ni] = mfma_bf16(af[i], bfr[ni], acc[i][ni]);
    }

    asm volatile("s_waitcnt vmcnt(0)" ::: "memory");
    __builtin_amdgcn_s_barrier();
  }

  // epilogue (global only)
  const int gmb = row0 + wm * 64;
  const int gnb = col0 + wn * 32;
#pragma unroll
  for (int mi = 0; mi < 4; ++mi)
#pragma unroll
    for (int ni = 0; ni < 2; ++ni) {
      const int gm = gmb + mi * 16 + lg * 4;
      const int gn = gnb + ni * 16 + lc;
      const float bv = bias[gn];
      f32x4 v = acc[mi][ni];
#pragma unroll
      for (int r = 0; r < 4; ++r) C[(size_t)(gm + r) * 512 + gn] = v[r] + bv;
    }
}

// ---------------- launch ----------------
extern "C" void kernel_launch(void* const* d_in, const int* in_sizes, int n_in,
                              void* d_out, int out_size, void* d_ws, size_t ws_size,
                              hipStream_t stream) {
  const float* x        = (const float*)d_in[0];
  const float* pos_bias = (const float*)d_in[1];
  const float* Wq       = (const float*)d_in[2];
  const float* Wk       = (const float*)d_in[3];
  const float* Wv       = (const float*)d_in[4];
  const float* Wo       = (const float*)d_in[5];
  const float* bo       = (const float*)d_in[6];
  float* out            = (float*)d_out;

  u16* xb      = (u16*)d_ws;                           // [65536][512]
  u16* attnbuf = xb + (size_t)M_ROWS * 512;            // [65536][512]
  u16* Wo_t    = attnbuf + (size_t)M_ROWS * 512;       // [512][512]
  u16* Wqkv_t  = (u16*)d_out;                          // [1536][512] (dead until GEMM2)

  conv_x<<<dim3(M_ROWS * KDIM / (256 * 8)), dim3(256), 0, stream>>>(x, xb);
  convW_qkv_t<<<dim3(48, 16), dim3(256), 0, stream>>>(Wq, Wk, Wv, Wqkv_t);
  gemm_qkv_attn<<<dim3(4096), dim3(512), 0, stream>>>(xb, Wqkv_t, pos_bias, attnbuf);
  convWo_t<<<dim3(16, 16), dim3(256), 0, stream>>>(Wo, Wo_t);
  gemm_out<<<dim3(2048), dim3(512), 0, stream>>>(attnbuf, Wo_t, out, bo);
}

// Round 17
// 210.237 us; speedup vs baseline: 1.6473x; 1.5598x over previous
//
#include <hip/hip_runtime.h>

typedef unsigned short u16;
typedef __attribute__((ext_vector_type(8))) unsigned short u16x8;
typedef __attribute__((ext_vector_type(8))) __bf16 bf16x8;
typedef __attribute__((ext_vector_type(4))) float f32x4;

#define M_ROWS 65536   // b*s*f
#define KDIM   512
#define NKT    8       // KDIM / 64

typedef __attribute__((address_space(1))) const void gconst_void;
typedef __attribute__((address_space(3))) void lds_void;

static __device__ __forceinline__ u16 f2bf(float f) {
  unsigned u = __builtin_bit_cast(unsigned, f);
  u += 0x7FFFu + ((u >> 16) & 1u);
  return (u16)(u >> 16);
}

static __device__ __forceinline__ f32x4 mfma_bf16(u16x8 a, u16x8 b, f32x4 c) {
  return __builtin_amdgcn_mfma_f32_16x16x32_bf16(
      __builtin_bit_cast(bf16x8, a), __builtin_bit_cast(bf16x8, b), c, 0, 0, 0);
}

// ---------------- fp32 -> bf16 convert (x) ----------------
__global__ void conv_x(const float* __restrict__ x, u16* __restrict__ xb) {
  const size_t t = (size_t)blockIdx.x * 256 + threadIdx.x;
  f32x4 a = *(const f32x4*)(x + t * 8);
  f32x4 b = *(const f32x4*)(x + t * 8 + 4);
  u16x8 w;
#pragma unroll
  for (int e = 0; e < 4; ++e) { w[e] = f2bf(a[e]); w[e + 4] = f2bf(b[e]); }
  *(u16x8*)(xb + t * 8) = w;
}

// ------ weight transpose+convert, LDS-tiled ------
__global__ void convW_qkv_t(const float* __restrict__ Wq, const float* __restrict__ Wk,
                            const float* __restrict__ Wv, u16* __restrict__ Wt) {
  __shared__ float tile[32][33];
  const int bn = blockIdx.x * 32;
  const int bk = blockIdx.y * 32;
  const int tx = threadIdx.x & 31, ty = threadIdx.x >> 5;
  const float* W = (bn < 512) ? Wq : ((bn < 1024) ? Wk : Wv);
  const int coln = bn & 511;
#pragma unroll
  for (int r = 0; r < 32; r += 8)
    tile[ty + r][tx] = W[(size_t)(bk + ty + r) * 512 + coln + tx];
  __syncthreads();
#pragma unroll
  for (int r = 0; r < 32; r += 8)
    Wt[(size_t)(bn + ty + r) * 512 + bk + tx] = f2bf(tile[tx][ty + r]);
}

__global__ void convWo_t(const float* __restrict__ Wo, u16* __restrict__ Wt) {
  __shared__ float tile[32][33];
  const int bn = blockIdx.x * 32;
  const int bk = blockIdx.y * 32;
  const int tx = threadIdx.x & 31, ty = threadIdx.x >> 5;
#pragma unroll
  for (int r = 0; r < 32; r += 8)
    tile[ty + r][tx] = Wo[(size_t)(bk + ty + r) * 512 + bn + tx];
  __syncthreads();
#pragma unroll
  for (int r = 0; r < 32; r += 8)
    Wt[(size_t)(bn + ty + r) * 512 + bk + tx] = f2bf(tile[tx][ty + r]);
}

// -------- FUSED qkv projection (one head) + attention, BM=128, 2 blk/CU ---
// r13 CHAMPION, verbatim (126us, Occ 41.7%, MfmaUtil 37.7%).  B stays in
// LDS: both register-B variants failed (r15 unpipelined: L2-latency-bound,
// +109us; r16 pipelined: register spill to scratch, WRITE_SIZE 3x).
// Levers exhausted on this structure: 7 schedule variants (r4-r12),
// occupancy (r13 captured it), LDS-traffic (r15/r16 negative).
__global__ __launch_bounds__(512, 4)
void gemm_qkv_attn(const u16* __restrict__ A, const u16* __restrict__ Wt,
                   const float* __restrict__ pos_bias, u16* __restrict__ attnbuf) {
  __shared__ __attribute__((aligned(16))) u16 smem[40960];  // 80 KiB
  u16* Ab   = smem;            // [2][8192]
  u16* Bb   = smem + 16384;    // [2][12288]
  u16* qkvT = smem;            // [128][200] = 25600 (post-loop alias)
  u16* Pl   = smem + 25600;    // [8][256]  = 2048

  const int tid  = threadIdx.x;
  const int lane = tid & 63;
  const int wid  = tid >> 6;        // 0..7
  const int wm   = wid >> 2;        // 0..1 (64-row band)
  const int wn   = wid & 3;         // 0..3 (48-col band)
  const int lg   = lane >> 4;
  const int lc   = lane & 15;
  const int srow = lane >> 3;       // 0..7
  const int sg   = (lane & 7) ^ srow;

  const int nwg  = gridDim.x;       // 4096
  const int cpx  = nwg >> 3;
  const int flat = blockIdx.x;
  const int swz  = (flat & 7) * cpx + (flat >> 3);
  const int mt   = swz >> 3;
  const int h    = swz & 7;
  const int row0 = mt * 128;

  auto stageA = [&](int buf, int unit, int kt) {
    const int rl = unit * 64 + wid * 8;
    const u16* src = A + (size_t)(row0 + rl + srow) * KDIM + kt * 64 + sg * 8;
    __builtin_amdgcn_global_load_lds((gconst_void*)src,
                                     (lds_void*)&Ab[buf * 8192 + rl * 64], 16, 0, 0);
  };
  auto stageB = [&](int buf, int unit, int kt) {
    const int rl = unit * 64 + wid * 8;
    const int grow = unit * 512 + h * 64 + wid * 8 + srow;
    const u16* src = Wt + (size_t)grow * KDIM + kt * 64 + sg * 8;
    __builtin_amdgcn_global_load_lds((gconst_void*)src,
                                     (lds_void*)&Bb[buf * 12288 + rl * 64], 16, 0, 0);
  };

  f32x4 acc[4][3];
#pragma unroll
  for (int mi = 0; mi < 4; ++mi)
#pragma unroll
    for (int ni = 0; ni < 3; ++ni) acc[mi][ni] = (f32x4){0.f, 0.f, 0.f, 0.f};

  stageA(0, 0, 0); stageA(0, 1, 0);
  stageB(0, 0, 0); stageB(0, 1, 0); stageB(0, 2, 0);
  asm volatile("s_waitcnt vmcnt(0)" ::: "memory");
  __builtin_amdgcn_s_barrier();

  for (int t = 0; t < NKT; ++t) {
    const int  c   = t & 1;
    const bool pre = (t + 1) < NKT;

    if (pre) {
      stageA(c ^ 1, 0, t + 1); stageA(c ^ 1, 1, t + 1);
      stageB(c ^ 1, 0, t + 1); stageB(c ^ 1, 1, t + 1); stageB(c ^ 1, 2, t + 1);
    }

#pragma unroll
    for (int ks = 0; ks < 2; ++ks) {
      const int gsw = ((ks * 4 + lg) ^ (lc & 7)) << 3;
      u16x8 bfr[3], af[4];
#pragma unroll
      for (int ni = 0; ni < 3; ++ni)
        bfr[ni] = *(const u16x8*)&Bb[c * 12288 + (wn * 48 + ni * 16 + lc) * 64 + gsw];
#pragma unroll
      for (int i = 0; i < 4; ++i)
        af[i] = *(const u16x8*)&Ab[c * 8192 + (wm * 64 + i * 16 + lc) * 64 + gsw];
#pragma unroll
      for (int i = 0; i < 4; ++i)
#pragma unroll
        for (int ni = 0; ni < 3; ++ni)
          acc[i][ni] = mfma_bf16(af[i], bfr[ni], acc[i][ni]);
    }

    asm volatile("s_waitcnt vmcnt(0)" ::: "memory");
    __builtin_amdgcn_s_barrier();
  }

  // ---- epilogue: acc -> bf16 -> qkvT[128][200] ----
#pragma unroll
  for (int mi = 0; mi < 4; ++mi)
#pragma unroll
    for (int ni = 0; ni < 3; ++ni) {
      const int col = wn * 48 + ni * 16 + lc;
      const int rb  = wm * 64 + mi * 16 + lg * 4;
#pragma unroll
      for (int r = 0; r < 4; ++r)
        qkvT[(rb + r) * 200 + col] = f2bf(acc[mi][ni][r]);
    }
  __syncthreads();

  // ---- attention (verified math): one token per wave ----
  const float scale = 0.125f;
  const f32x4 zf = {0.f, 0.f, 0.f, 0.f};
  const int rb = wid * 16;
  const int qb = (rb + lc) * 200;

  u16x8 aq0 = *(const u16x8*)&qkvT[qb + 0  + lg * 8];
  u16x8 aq1 = *(const u16x8*)&qkvT[qb + 32 + lg * 8];
  u16x8 bk0 = *(const u16x8*)&qkvT[qb + 64 + lg * 8];
  u16x8 bk1 = *(const u16x8*)&qkvT[qb + 96 + lg * 8];
  f32x4 s = mfma_bf16(aq0, bk0, zf);
  s = mfma_bf16(aq1, bk1, s);

  const int pb = wid * 256;
#pragma unroll
  for (int r = 0; r < 4; ++r) {
    const int i = lg * 4 + r;
    float sv = s[r] * scale + pos_bias[h * 256 + i * 16 + lc];
    if (lc > i) sv = -1e30f;
    float m = sv;
#pragma unroll
    for (int off = 8; off >= 1; off >>= 1) m = fmaxf(m, __shfl_xor(m, off));
    float e = __expf(sv - m);
    float sm = e;
#pragma unroll
    for (int off = 8; off >= 1; off >>= 1) sm += __shfl_xor(sm, off);
    Pl[pb + i * 16 + lc] = f2bf(e / sm);
  }
  asm volatile("s_waitcnt lgkmcnt(0)" ::: "memory");

  u16x8 ap = {0, 0, 0, 0, 0, 0, 0, 0};
  if (lane < 32) ap = *(const u16x8*)&Pl[pb + lc * 16 + lg * 8];

#pragma unroll
  for (int nd = 0; nd < 4; ++nd) {
    u16x8 bv = {0, 0, 0, 0, 0, 0, 0, 0};
    if (lane < 32) {
#pragma unroll
      for (int jj = 0; jj < 8; ++jj) {
        const int j = lg * 8 + jj;
        bv[jj] = qkvT[(rb + j) * 200 + 128 + nd * 16 + lc];
      }
    }
    f32x4 o = mfma_bf16(ap, bv, zf);
#pragma unroll
    for (int r = 0; r < 4; ++r) {
      const int i = lg * 4 + r;
      attnbuf[(size_t)(row0 + rb + i) * 512 + h * 64 + nd * 16 + lc] = f2bf(o[r]);
    }
  }
}

// -------- GEMM2: out = attnbuf @ Wo_t^T + bo, 128x128, 2 blk/CU -----
// (r14 measured form: B in LDS, 64 KiB, simple tile-top sync.)
__global__ __launch_bounds__(512, 4)
void gemm_out(const u16* __restrict__ A, const u16* __restrict__ Bt,
              float* __restrict__ C, const float* __restrict__ bias) {
  __shared__ __attribute__((aligned(16))) u16 smem[32768];  // 64 KiB
  u16* Ab = smem;            // [2][8192]
  u16* Bb = smem + 16384;    // [2][8192]

  const int tid  = threadIdx.x;
  const int lane = tid & 63;
  const int wid  = tid >> 6;
  const int wm   = wid >> 2;        // 0..1 (64-row band)
  const int wn   = wid & 3;         // 0..3 (32-col band)
  const int lg   = lane >> 4;
  const int lc   = lane & 15;
  const int srow = lane >> 3;
  const int sg   = (lane & 7) ^ srow;

  const int nwg  = gridDim.x;       // 2048
  const int cpx  = nwg >> 3;
  const int flat = blockIdx.x;
  const int swz  = (flat & 7) * cpx + (flat >> 3);
  const int mt   = swz >> 2;        // 0..511
  const int nt   = swz & 3;         // 0..3
  const int row0 = mt * 128, col0 = nt * 128;

  auto stageA = [&](int buf, int unit, int kt) {
    const int rl = unit * 64 + wid * 8;
    const u16* src = A + (size_t)(row0 + rl + srow) * KDIM + kt * 64 + sg * 8;
    __builtin_amdgcn_global_load_lds((gconst_void*)src,
                                     (lds_void*)&Ab[buf * 8192 + rl * 64], 16, 0, 0);
  };
  auto stageB = [&](int buf, int unit, int kt) {
    const int rl = unit * 64 + wid * 8;
    const u16* src = Bt + (size_t)(col0 + rl + srow) * KDIM + kt * 64 + sg * 8;
    __builtin_amdgcn_global_load_lds((gconst_void*)src,
                                     (lds_void*)&Bb[buf * 8192 + rl * 64], 16, 0, 0);
  };

  f32x4 acc[4][2];
#pragma unroll
  for (int mi = 0; mi < 4; ++mi)
#pragma unroll
    for (int ni = 0; ni < 2; ++ni) acc[mi][ni] = (f32x4){0.f, 0.f, 0.f, 0.f};

  stageA(0, 0, 0); stageA(0, 1, 0);
  stageB(0, 0, 0); stageB(0, 1, 0);
  asm volatile("s_waitcnt vmcnt(0)" ::: "memory");
  __builtin_amdgcn_s_barrier();

  for (int t = 0; t < NKT; ++t) {
    const int  c   = t & 1;
    const bool pre = (t + 1) < NKT;

    if (pre) {
      stageA(c ^ 1, 0, t + 1); stageA(c ^ 1, 1, t + 1);
      stageB(c ^ 1, 0, t + 1); stageB(c ^ 1, 1, t + 1);
    }

#pragma unroll
    for (int ks = 0; ks < 2; ++ks) {
      const int gsw = ((ks * 4 + lg) ^ (lc & 7)) << 3;
      u16x8 bfr[2], af[4];
#pragma unroll
      for (int ni = 0; ni < 2; ++ni)
        bfr[ni] = *(const u16x8*)&Bb[c * 8192 + (wn * 32 + ni * 16 + lc) * 64 + gsw];
#pragma unroll
      for (int i = 0; i < 4; ++i)
        af[i] = *(const u16x8*)&Ab[c * 8192 + (wm * 64 + i * 16 + lc) * 64 + gsw];
#pragma unroll
      for (int i = 0; i < 4; ++i)
#pragma unroll
        for (int ni = 0; ni < 2; ++ni)
          acc[i][ni] = mfma_bf16(af[i], bfr[ni], acc[i][ni]);
    }

    asm volatile("s_waitcnt vmcnt(0)" ::: "memory");
    __builtin_amdgcn_s_barrier();
  }

  // epilogue (global only)
  const int gmb = row0 + wm * 64;
  const int gnb = col0 + wn * 32;
#pragma unroll
  for (int mi = 0; mi < 4; ++mi)
#pragma unroll
    for (int ni = 0; ni < 2; ++ni) {
      const int gm = gmb + mi * 16 + lg * 4;
      const int gn = gnb + ni * 16 + lc;
      const float bv = bias[gn];
      f32x4 v = acc[mi][ni];
#pragma unroll
      for (int r = 0; r < 4; ++r) C[(size_t)(gm + r) * 512 + gn] = v[r] + bv;
    }
}

// ---------------- launch ----------------
extern "C" void kernel_launch(void* const* d_in, const int* in_sizes, int n_in,
                              void* d_out, int out_size, void* d_ws, size_t ws_size,
                              hipStream_t stream) {
  const float* x        = (const float*)d_in[0];
  const float* pos_bias = (const float*)d_in[1];
  const float* Wq       = (const float*)d_in[2];
  const float* Wk       = (const float*)d_in[3];
  const float* Wv       = (const float*)d_in[4];
  const float* Wo       = (const float*)d_in[5];
  const float* bo       = (const float*)d_in[6];
  float* out            = (float*)d_out;

  u16* xb      = (u16*)d_ws;                           // [65536][512]
  u16* attnbuf = xb + (size_t)M_ROWS * 512;            // [65536][512]
  u16* Wo_t    = attnbuf + (size_t)M_ROWS * 512;       // [512][512]
  u16* Wqkv_t  = (u16*)d_out;                          // [1536][512] (dead until GEMM2)

  conv_x<<<dim3(M_ROWS * KDIM / (256 * 8)), dim3(256), 0, stream>>>(x, xb);
  convW_qkv_t<<<dim3(48, 16), dim3(256), 0, stream>>>(Wq, Wk, Wv, Wqkv_t);
  gemm_qkv_attn<<<dim3(4096), dim3(512), 0, stream>>>(xb, Wqkv_t, pos_bias, attnbuf);
  convWo_t<<<dim3(16, 16), dim3(256), 0, stream>>>(Wo, Wo_t);
  gemm_out<<<dim3(2048), dim3(512), 0, stream>>>(attnbuf, Wo_t, out, bo);
}